// Round 1
// baseline (43.352 us; speedup 1.0000x reference)
//
#include <hip/hip_runtime.h>

#define D_MODEL 2048
#define EPS 1e-5f

// One block per row. 256 threads * 8 floats = 2048 elements.
// Thread t handles elements [t*4, t*4+4) and [1024 + t*4, 1024 + t*4 + 4)
// -> both float4 loads are perfectly coalesced (lane i at byte offset i*16).
__global__ __launch_bounds__(256) void rmsnorm_kernel(
    const float* __restrict__ x,
    const float* __restrict__ gain,
    float* __restrict__ out)
{
    const size_t row = blockIdx.x;
    const float* __restrict__ xr = x + row * (size_t)D_MODEL;
    float* __restrict__ orow = out + row * (size_t)D_MODEL;
    const int t = threadIdx.x;

    const float4 a = *reinterpret_cast<const float4*>(xr + t * 4);
    const float4 b = *reinterpret_cast<const float4*>(xr + 1024 + t * 4);

    float ss = a.x * a.x + a.y * a.y + a.z * a.z + a.w * a.w
             + b.x * b.x + b.y * b.y + b.z * b.z + b.w * b.w;

    // 64-lane wave butterfly reduction
    #pragma unroll
    for (int off = 32; off > 0; off >>= 1)
        ss += __shfl_xor(ss, off, 64);

    // cross-wave reduction (4 waves per block)
    __shared__ float wave_sums[4];
    const int lane = t & 63;
    const int wave = t >> 6;
    if (lane == 0) wave_sums[wave] = ss;
    __syncthreads();
    const float total = wave_sums[0] + wave_sums[1] + wave_sums[2] + wave_sums[3];

    const float scale = rsqrtf(total * (1.0f / (float)D_MODEL) + EPS);

    const float4 g0 = *reinterpret_cast<const float4*>(gain + t * 4);
    const float4 g1 = *reinterpret_cast<const float4*>(gain + 1024 + t * 4);

    float4 o0, o1;
    o0.x = a.x * scale * g0.x;
    o0.y = a.y * scale * g0.y;
    o0.z = a.z * scale * g0.z;
    o0.w = a.w * scale * g0.w;
    o1.x = b.x * scale * g1.x;
    o1.y = b.y * scale * g1.y;
    o1.z = b.z * scale * g1.z;
    o1.w = b.w * scale * g1.w;

    *reinterpret_cast<float4*>(orow + t * 4) = o0;
    *reinterpret_cast<float4*>(orow + 1024 + t * 4) = o1;
}

extern "C" void kernel_launch(void* const* d_in, const int* in_sizes, int n_in,
                              void* d_out, int out_size, void* d_ws, size_t ws_size,
                              hipStream_t stream) {
    const float* x = (const float*)d_in[0];
    const float* gain = (const float*)d_in[1];
    float* out = (float*)d_out;

    const int rows = in_sizes[0] / D_MODEL;  // 4*4096 = 16384
    rmsnorm_kernel<<<rows, 256, 0, stream>>>(x, gain, out);
}